// Round 18
// baseline (131.588 us; speedup 1.0000x reference)
//
#include <hip/hip_runtime.h>
#include <hip/hip_bf16.h>
#include <cmath>

#define R_ 64
#define B_ 4096
#define D_ 512
#define C_ 128

typedef __attribute__((ext_vector_type(8))) short bf16x8;
typedef __attribute__((ext_vector_type(4))) float f32x4;

__device__ __forceinline__ unsigned short f2bf(float f) {
  union { float f; unsigned u; } x; x.f = f;
  unsigned r = (x.u + 0x7FFFu + ((x.u >> 16) & 1u)) >> 16;
  return (unsigned short)r;
}

// ---------------- prep: W[r][d][c] f32 -> W^T[r][c][d] bf16 ----------------
__global__ void prep_w_kernel(const float* __restrict__ W, unsigned short* __restrict__ wt) {
  __shared__ float t[32][33];
  int bx = blockIdx.x;
  int r = bx >> 6;
  int rem = bx & 63;
  int d0 = (rem >> 2) << 5;   // 16 d-tiles of 32
  int c0 = (rem & 3) << 5;    // 4 c-tiles of 32
  int tx = threadIdx.x & 31, ty = threadIdx.x >> 5;  // 32 x 8
  const float* Wr = W + (size_t)r * D_ * C_;
#pragma unroll
  for (int q = 0; q < 4; ++q) {
    int dl = q * 8 + ty;
    t[dl][tx] = Wr[(size_t)(d0 + dl) * C_ + c0 + tx];
  }
  __syncthreads();
  unsigned short* wtr = wt + (size_t)r * C_ * D_;
#pragma unroll
  for (int q = 0; q < 4; ++q) {
    int cl = q * 8 + ty;
    float v = t[tx][cl];                         // transposed read, pad-33 conflict-free
    wtr[(size_t)(c0 + cl) * D_ + d0 + tx] = f2bf(v);
  }
}

// ---------------- prep: (s, -p*s) per (rule, dim) ----------------
__global__ void prep_ps_kernel(const float* __restrict__ proto, const float* __restrict__ var,
                               float* __restrict__ ps) {
  int i = blockIdx.x * 256 + threadIdx.x;          // R*D elements
  float v = fminf(fmaxf(var[i], 1e-4f), 0.1f);
  float s = 1.2011224087864498f / v;
  float2 o; o.x = s; o.y = -proto[i] * s;
  reinterpret_cast<float2*>(ps)[i] = o;
}

// ---------------- antecedent partial + fused x->bf16 emission ----------------
__global__ __launch_bounds__(256, 4) void fs_partial_kernel(
    const float* __restrict__ x, const float* __restrict__ ps,
    float* __restrict__ fire, unsigned short* __restrict__ xw) {
  __shared__ float x_s[16 * 68];
  __shared__ __align__(16) float ps_s[64 * 128];   // [rule][dim*2], XOR-swizzled granules
  const int tid = threadIdx.x;
  const int b0 = blockIdx.x * 16;
  const int dq = blockIdx.y;                       // dims dq*64 .. dq*64+63

  {  // stage x tile: 16 rows x 64 dims
    int row = tid >> 4, c4 = tid & 15;
    float4 v = *reinterpret_cast<const float4*>(&x[(size_t)(b0 + row) * D_ + dq * 64 + c4 * 4]);
    *reinterpret_cast<float4*>(&x_s[row * 68 + c4 * 4]) = v;
  }
#pragma unroll
  for (int k = 0; k < 8; ++k) {  // stage ps tile: 64 rules x 32 granules(16B), swizzled
    int g = tid + k * 256;
    int row = g >> 5, gi = g & 31;
    float4 v = *reinterpret_cast<const float4*>(&ps[(size_t)row * (D_ * 2) + dq * 128 + gi * 4]);
    int gs = gi ^ (row & 31);
    *reinterpret_cast<float4*>((char*)ps_s + row * 512 + (gs << 4)) = v;
  }
  __syncthreads();

  {  // fused prep_x: emit bf16 of this block's x tile (disjoint across grid)
    int row = tid >> 4, c0 = (tid & 15) * 4;
    const float* sp = &x_s[row * 68 + c0];
    ushort4 o;
    o.x = f2bf(sp[0]); o.y = f2bf(sp[1]); o.z = f2bf(sp[2]); o.w = f2bf(sp[3]);
    *reinterpret_cast<ushort4*>(&xw[(size_t)(b0 + row) * D_ + dq * 64 + c0]) = o;
  }

  const int tr = tid & 63;   // rule = lane
  const int tb = tid >> 6;   // wave -> 4 batch rows
  const int s31 = tr & 31;
  const char* pb = (const char*)ps_s + tr * 512;
  float facc[4] = {0.f, 0.f, 0.f, 0.f};

#pragma unroll
  for (int d4 = 0; d4 < 16; ++d4) {
    float4 psa = *reinterpret_cast<const float4*>(pb + ((((d4 * 2) ^ s31)) << 4));
    float4 psb = *reinterpret_cast<const float4*>(pb + ((((d4 * 2 + 1) ^ s31)) << 4));
#pragma unroll
    for (int i = 0; i < 4; ++i) {
      float4 xv = *reinterpret_cast<const float4*>(&x_s[(tb * 4 + i) * 68 + d4 * 4]);
      float u0 = fmaf(xv.x, psa.x, psa.y);
      float u1 = fmaf(xv.y, psa.z, psa.w);
      float u2 = fmaf(xv.z, psb.x, psb.y);
      float u3 = fmaf(xv.w, psb.z, psb.w);
      facc[i] += exp2f(-(u0 * u0)) + exp2f(-(u1 * u1)) +
                 exp2f(-(u2 * u2)) + exp2f(-(u3 * u3));
    }
  }
#pragma unroll
  for (int i = 0; i < 4; ++i)
    atomicAdd(&fire[(size_t)(b0 + tb * 4 + i) * R_ + tr], facc[i]);
}

// ---------------- softmax over rules, in place on fire buffer ----------------
__global__ void softmax_kernel(float* __restrict__ fire) {
  const int b = blockIdx.x * 4 + (threadIdx.x >> 6);
  const int r = threadIdx.x & 63;
  float v = fire[(size_t)b * R_ + r];
  float m = v;
#pragma unroll
  for (int off = 32; off; off >>= 1) m = fmaxf(m, __shfl_xor(m, off, 64));
  float e = exp2f((v - m) * 1.4426950408889634f);
  float s = e;
#pragma unroll
  for (int off = 32; off; off >>= 1) s += __shfl_xor(s, off, 64);
  fire[(size_t)b * R_ + r] = e / s;
}

// ---------------- fused rule-GEMM + relu + fire-weighted combine ----------------
// R13 reg-staging body, BK 64->32: LDS 38 KB + launch_bounds(512,6) -> 3 blocks/CU
// (24 waves vs R13's 16). More resident step-pipelines cover each other's load
// latency (m97 runs ~50 GB/s/CU at 3-4 blocks; R13 runs 30 at 2).
// BM=128, BN=C=128, BK=32, 4 rules/block. 8 waves (2x4), wave tile 64x32.
// Swizzle for 64B rows: perm = g ^ (row&3) ^ ((row>>2)&3) -> worst 2-way (free).
__global__ __launch_bounds__(512, 6) void gemm_kernel(
    const unsigned short* __restrict__ xw, const unsigned short* __restrict__ wt,
    const float* __restrict__ fire, const float* __restrict__ bias,
    float* __restrict__ out) {
  __shared__ __align__(16) unsigned short x_s[2][128 * 32];   // 2 x 8 KB
  __shared__ __align__(16) unsigned short w_s[2][128 * 32];   // 2 x 8 KB
  __shared__ float fire_s[128 * 4];                           // 2 KB
  __shared__ float bias_s[4 * 128];                           // 2 KB

  const int tid = threadIdx.x;       // 0..511
  // 1D XCD decode (R13's, proven with 67 us): xcd owns rgs {2k, 2k+1}
  const int f = blockIdx.x;          // 0..511
  const int xcd = f & 7;
  const int idx = f >> 3;            // 0..63
  const int rg = 2 * xcd + (idx & 1);
  const int bm = idx >> 1;           // 0..31
  const int b0 = bm * 128;

  {
    int row = tid >> 2, g = tid & 3;
    fire_s[tid] = fire[(size_t)(b0 + row) * R_ + rg * 4 + g];
    bias_s[tid] = bias[rg * 4 * C_ + tid];
  }

  const int wid = tid >> 6, lane = tid & 63;
  const int wm = wid >> 2, wn = wid & 3;           // 2 x 4 wave grid, wave tile 64x32
  const int l16 = lane & 15, lhi = lane >> 4;      // lhi = granule 0..3 (8 bf16 each)

  // ds_read byte offsets (swizzled 16B granules within 64B rows)
  int offA[4], offB[2];
#pragma unroll
  for (int m = 0; m < 4; ++m) {
    int row = wm * 64 + m * 16 + l16;              // 0..127
    int perm = lhi ^ (row & 3) ^ ((row >> 2) & 3);
    offA[m] = row * 64 + (perm << 4);
  }
#pragma unroll
  for (int n = 0; n < 2; ++n) {
    int row = wn * 32 + n * 16 + l16;              // 0..127
    int perm = lhi ^ (row & 3) ^ ((row >> 2) & 3);
    offB[n] = row * 64 + (perm << 4);
  }

  // staging chunk maps: 512 chunks each for A and B; 1 per thread each.
  // global offset LINEAR, LDS dest swizzled (same perm as reads).
  int a_goff, a_ldst, b_goff, b_ldst;
  {
    int ch = tid;
    int row = ch >> 2, g = ch & 3;
    int perm = g ^ (row & 3) ^ ((row >> 2) & 3);
    a_goff = row * D_ + g * 8;
    a_ldst = row * 64 + (perm << 4);
    b_goff = a_goff;
    b_ldst = a_ldst;
  }

  const unsigned short* xsrc = xw + (size_t)b0 * D_;
  const unsigned short* wbase = wt + (size_t)(rg * 4) * C_ * D_;

  float tot[4][2][4];
#pragma unroll
  for (int m = 0; m < 4; ++m)
#pragma unroll
    for (int n = 0; n < 2; ++n)
#pragma unroll
      for (int j = 0; j < 4; ++j) tot[m][n][j] = 0.f;

  f32x4 acc[4][2];

  // prologue: stage tile 0 via regs
  {
    uint4 la = *reinterpret_cast<const uint4*>(xsrc + a_goff);
    uint4 lb = *reinterpret_cast<const uint4*>(wbase + b_goff);
    *reinterpret_cast<uint4*>((char*)x_s[0] + a_ldst) = la;
    *reinterpret_cast<uint4*>((char*)w_s[0] + b_ldst) = lb;
  }
  __syncthreads();

  int cur = 0;
  for (int s = 0; s < 64; ++s) {                   // s = rule*16 + kc
    const int g = s >> 4, kk = s & 15;
    if (kk == 0) {
#pragma unroll
      for (int m = 0; m < 4; ++m)
#pragma unroll
        for (int n = 0; n < 2; ++n)
          acc[m][n] = f32x4{0.f, 0.f, 0.f, 0.f};
    }
    // issue next tile's global loads early (overlap with ds_read+MFMA below)
    uint4 la, lb;
    if (s + 1 < 64) {
      const int s1 = s + 1;
      la = *reinterpret_cast<const uint4*>(xsrc + (s1 & 15) * 32 + a_goff);
      lb = *reinterpret_cast<const uint4*>(
          wbase + (size_t)(s1 >> 4) * C_ * D_ + (s1 & 15) * 32 + b_goff);
    }
    const char* xb = (const char*)x_s[cur];
    const char* wb = (const char*)w_s[cur];
    {
      bf16x8 av[4], bv[2];
#pragma unroll
      for (int m = 0; m < 4; ++m)
        av[m] = *reinterpret_cast<const bf16x8*>(xb + offA[m]);
#pragma unroll
      for (int n = 0; n < 2; ++n)
        bv[n] = *reinterpret_cast<const bf16x8*>(wb + offB[n]);
#pragma unroll
      for (int m = 0; m < 4; ++m)
#pragma unroll
        for (int n = 0; n < 2; ++n)
          acc[m][n] = __builtin_amdgcn_mfma_f32_16x16x32_bf16(av[m], bv[n], acc[m][n], 0, 0, 0);
    }
    if (kk == 15) {  // rule g finished: relu(+bias) * fire, accumulate
#pragma unroll
      for (int m = 0; m < 4; ++m)
#pragma unroll
        for (int n = 0; n < 2; ++n) {
          int col = wn * 32 + n * 16 + l16;
          float bi = bias_s[g * 128 + col];
#pragma unroll
          for (int j = 0; j < 4; ++j) {
            int rowl = wm * 64 + m * 16 + lhi * 4 + j;
            float v = acc[m][n][j] + bi;
            v = fmaxf(v, 0.f);
            tot[m][n][j] += v * fire_s[rowl * 4 + g];
          }
        }
    }
    if (s + 1 < 64) {
      // compiler inserts vmcnt waits on la/lb use; writes target buf^1 whose
      // readers all passed the previous barrier.
      *reinterpret_cast<uint4*>((char*)x_s[cur ^ 1] + a_ldst) = la;
      *reinterpret_cast<uint4*>((char*)w_s[cur ^ 1] + b_ldst) = lb;
    }
    __syncthreads();
    cur ^= 1;
  }

#pragma unroll
  for (int m = 0; m < 4; ++m)
#pragma unroll
    for (int n = 0; n < 2; ++n) {
      int col = wn * 32 + n * 16 + l16;
#pragma unroll
      for (int j = 0; j < 4; ++j) {
        int rowl = wm * 64 + m * 16 + lhi * 4 + j;
        atomicAdd(&out[(size_t)(b0 + rowl) * C_ + col], tot[m][n][j]);
      }
    }
}

extern "C" void kernel_launch(void* const* d_in, const int* in_sizes, int n_in,
                              void* d_out, int out_size, void* d_ws, size_t ws_size,
                              hipStream_t stream) {
  const float* x     = (const float*)d_in[0];
  const float* proto = (const float*)d_in[1];
  const float* var   = (const float*)d_in[2];
  const float* W     = (const float*)d_in[3];
  const float* bias  = (const float*)d_in[4];
  float* out  = (float*)d_out;
  float* fire = out + (size_t)B_ * C_;   // second output region (also fs_ini accumulator)

  const size_t WS_X  = (size_t)B_ * D_ * sizeof(unsigned short);       // 4 MiB
  const size_t WS_WT = (size_t)R_ * C_ * D_ * sizeof(unsigned short);  // 8 MiB
  const size_t WS_PS = (size_t)R_ * D_ * 2 * sizeof(float);            // 256 KiB
  if (ws_size < WS_X + WS_WT + WS_PS) return;  // insufficient scratch -> visible failure

  unsigned short* xw  = (unsigned short*)d_ws;
  unsigned short* wtp = (unsigned short*)((char*)d_ws + WS_X);
  float*          ps  = (float*)((char*)d_ws + WS_X + WS_WT);

  // zero BOTH output regions: out accumulates gemm atomics, fire accumulates fs partials
  hipMemsetAsync(d_out, 0, (size_t)out_size * sizeof(float), stream);
  prep_w_kernel<<<dim3(R_ * 64), dim3(256), 0, stream>>>(W, wtp);
  prep_ps_kernel<<<dim3(R_ * D_ / 256), dim3(256), 0, stream>>>(proto, var, ps);
  fs_partial_kernel<<<dim3(B_ / 16, 8), dim3(256), 0, stream>>>(x, ps, fire, xw);
  softmax_kernel<<<dim3(B_ / 4), dim3(256), 0, stream>>>(fire);
  gemm_kernel<<<dim3(512), dim3(512), 0, stream>>>(xw, wtp, fire, bias, out);
}

// Round 19
// 112.683 us; speedup vs baseline: 1.1678x; 1.1678x over previous
//
#include <hip/hip_runtime.h>
#include <hip/hip_bf16.h>
#include <cmath>

#define R_ 64
#define B_ 4096
#define D_ 512
#define C_ 128

typedef __attribute__((ext_vector_type(8))) short bf16x8;
typedef __attribute__((ext_vector_type(4))) float f32x4;

__device__ __forceinline__ unsigned short f2bf(float f) {
  union { float f; unsigned u; } x; x.f = f;
  unsigned r = (x.u + 0x7FFFu + ((x.u >> 16) & 1u)) >> 16;
  return (unsigned short)r;
}

// ---------------- merged prep: W transpose->bf16  +  (s,-p*s) table ----------------
// blocks 0..4095: W[r][d][c] f32 -> W^T[r][c][d] bf16 (LDS 32x33 transpose)
// blocks 4096..4223: ps[i] = (s, -p*s), s = sqrt(log2 e)/clip(var)
__global__ __launch_bounds__(256) void prep_wps_kernel(
    const float* __restrict__ W, unsigned short* __restrict__ wt,
    const float* __restrict__ proto, const float* __restrict__ var,
    float* __restrict__ ps) {
  __shared__ float t[32][33];
  const int bx = blockIdx.x;
  if (bx >= 4096) {
    int i = (bx - 4096) * 256 + threadIdx.x;     // R*D elements
    float v = fminf(fmaxf(var[i], 1e-4f), 0.1f);
    float s = 1.2011224087864498f / v;
    float2 o; o.x = s; o.y = -proto[i] * s;
    reinterpret_cast<float2*>(ps)[i] = o;
    return;
  }
  int r = bx >> 6;
  int rem = bx & 63;
  int d0 = (rem >> 2) << 5;   // 16 d-tiles of 32
  int c0 = (rem & 3) << 5;    // 4 c-tiles of 32
  int tx = threadIdx.x & 31, ty = threadIdx.x >> 5;  // 32 x 8
  const float* Wr = W + (size_t)r * D_ * C_;
#pragma unroll
  for (int q = 0; q < 4; ++q) {
    int dl = q * 8 + ty;
    t[dl][tx] = Wr[(size_t)(d0 + dl) * C_ + c0 + tx];
  }
  __syncthreads();
  unsigned short* wtr = wt + (size_t)r * C_ * D_;
#pragma unroll
  for (int q = 0; q < 4; ++q) {
    int cl = q * 8 + ty;
    float v = t[tx][cl];                         // transposed read, pad-33 conflict-free
    wtr[(size_t)(c0 + cl) * D_ + d0 + tx] = f2bf(v);
  }
}

// ---------------- antecedent partial + fused x->bf16 emission ----------------
// dq split 16 (32 dims/block): LDS 19 KB -> 8 blocks/CU (100% occupancy).
// grid (256, 16); disjoint (rows x dims) coverage -> x read once, bf16 emitted once.
__global__ __launch_bounds__(256, 8) void fs_partial_kernel(
    const float* __restrict__ x, const float* __restrict__ ps,
    float* __restrict__ fire, unsigned short* __restrict__ xw) {
  __shared__ float x_s[16 * 36];
  __shared__ __align__(16) float ps_s[64 * 64];    // [rule][dim*2] 256B rows, swizzled granules
  const int tid = threadIdx.x;
  const int b0 = blockIdx.x * 16;
  const int dq = blockIdx.y;                       // dims dq*32 .. dq*32+31

  if (tid < 128) {  // stage x tile: 16 rows x 32 dims (128 float4)
    int row = tid >> 3, c4 = tid & 7;
    float4 v = *reinterpret_cast<const float4*>(&x[(size_t)(b0 + row) * D_ + dq * 32 + c4 * 4]);
    *reinterpret_cast<float4*>(&x_s[row * 36 + c4 * 4]) = v;
  }
#pragma unroll
  for (int k = 0; k < 4; ++k) {  // stage ps tile: 64 rules x 16 granules(16B), swizzled
    int g = tid + k * 256;
    int row = g >> 4, gi = g & 15;
    float4 v = *reinterpret_cast<const float4*>(&ps[(size_t)row * (D_ * 2) + dq * 64 + gi * 4]);
    int gs = gi ^ (row & 15);
    *reinterpret_cast<float4*>((char*)ps_s + row * 256 + (gs << 4)) = v;
  }
  __syncthreads();

  if (tid < 128) {  // fused prep_x: emit bf16 of this block's x tile
    int row = tid >> 3, c0 = (tid & 7) * 4;
    const float* sp = &x_s[row * 36 + c0];
    ushort4 o;
    o.x = f2bf(sp[0]); o.y = f2bf(sp[1]); o.z = f2bf(sp[2]); o.w = f2bf(sp[3]);
    *reinterpret_cast<ushort4*>(&xw[(size_t)(b0 + row) * D_ + dq * 32 + c0]) = o;
  }

  const int tr = tid & 63;   // rule = lane
  const int tb = tid >> 6;   // wave -> 4 batch rows
  const int s15 = tr & 15;
  const char* pb = (const char*)ps_s + tr * 256;
  float facc[4] = {0.f, 0.f, 0.f, 0.f};

#pragma unroll
  for (int d4 = 0; d4 < 8; ++d4) {
    float4 psa = *reinterpret_cast<const float4*>(pb + ((((d4 * 2) ^ s15)) << 4));
    float4 psb = *reinterpret_cast<const float4*>(pb + ((((d4 * 2 + 1) ^ s15)) << 4));
#pragma unroll
    for (int i = 0; i < 4; ++i) {
      float4 xv = *reinterpret_cast<const float4*>(&x_s[(tb * 4 + i) * 36 + d4 * 4]);
      float u0 = fmaf(xv.x, psa.x, psa.y);
      float u1 = fmaf(xv.y, psa.z, psa.w);
      float u2 = fmaf(xv.z, psb.x, psb.y);
      float u3 = fmaf(xv.w, psb.z, psb.w);
      facc[i] += exp2f(-(u0 * u0)) + exp2f(-(u1 * u1)) +
                 exp2f(-(u2 * u2)) + exp2f(-(u3 * u3));
    }
  }
#pragma unroll
  for (int i = 0; i < 4; ++i)
    atomicAdd(&fire[(size_t)(b0 + tb * 4 + i) * R_ + tr], facc[i]);
}

// ---------------- softmax over rules, in place on fire buffer ----------------
__global__ void softmax_kernel(float* __restrict__ fire) {
  const int b = blockIdx.x * 4 + (threadIdx.x >> 6);
  const int r = threadIdx.x & 63;
  float v = fire[(size_t)b * R_ + r];
  float m = v;
#pragma unroll
  for (int off = 32; off; off >>= 1) m = fmaxf(m, __shfl_xor(m, off, 64));
  float e = exp2f((v - m) * 1.4426950408889634f);
  float s = e;
#pragma unroll
  for (int off = 32; off; off >>= 1) s += __shfl_xor(s, off, 64);
  fire[(size_t)b * R_ + r] = e / s;
}

// ---------------- fused rule-GEMM + relu + fire-weighted combine ----------------
// R13 reg-staging body EXACTLY (67 us proven): global_load_dwordx4 -> VGPR ->
// swizzled ds_write, depth-1 prefetch. BM=128, BN=C=128, BK=64, 4 rules/block.
// 8 waves (2x4), wave tile 64x32.
__global__ __launch_bounds__(512, 4) void gemm_kernel(
    const unsigned short* __restrict__ xw, const unsigned short* __restrict__ wt,
    const float* __restrict__ fire, const float* __restrict__ bias,
    float* __restrict__ out) {
  __shared__ __align__(16) unsigned short x_s[2][128 * 64];   // 2 x 16 KB
  __shared__ __align__(16) unsigned short w_s[2][128 * 64];   // 2 x 16 KB
  __shared__ float fire_s[128 * 4];
  __shared__ float bias_s[4 * 128];

  const int tid = threadIdx.x;       // 0..511
  const int f = blockIdx.x;          // 0..511 (1D XCD decode)
  const int xcd = f & 7;
  const int idx = f >> 3;            // 0..63
  const int rg = 2 * xcd + (idx & 1);
  const int bm = idx >> 1;           // 0..31
  const int b0 = bm * 128;

  {
    int row = tid >> 2, g = tid & 3;
    fire_s[tid] = fire[(size_t)(b0 + row) * R_ + rg * 4 + g];
    bias_s[tid] = bias[rg * 4 * C_ + tid];
  }

  const int wid = tid >> 6, lane = tid & 63;
  const int wm = wid >> 2, wn = wid & 3;           // 2 x 4 wave grid, wave tile 64x32
  const int l16 = lane & 15, lhi = lane >> 4;

  int offA[4][2], offB[2][2];
#pragma unroll
  for (int m = 0; m < 4; ++m) {
    int row = wm * 64 + m * 16 + l16;              // 0..127
#pragma unroll
    for (int ks = 0; ks < 2; ++ks)
      offA[m][ks] = row * 128 + (((ks * 4 + lhi) ^ (row & 7)) << 4);
  }
#pragma unroll
  for (int n = 0; n < 2; ++n) {
    int row = wn * 32 + n * 16 + l16;              // 0..127
#pragma unroll
    for (int ks = 0; ks < 2; ++ks)
      offB[n][ks] = row * 128 + (((ks * 4 + lhi) ^ (row & 7)) << 4);
  }

  int a_goff[2], a_ldst[2], b_goff[2], b_ldst[2];
#pragma unroll
  for (int q = 0; q < 2; ++q) {
    int ch = q * 512 + tid;
    int row = ch >> 3, g = ch & 7;
    a_goff[q] = row * D_ + g * 8;
    a_ldst[q] = row * 128 + ((g ^ (row & 7)) << 4);
    b_goff[q] = row * D_ + g * 8;
    b_ldst[q] = row * 128 + ((g ^ (row & 7)) << 4);
  }

  const unsigned short* xsrc = xw + (size_t)b0 * D_;
  const unsigned short* wbase = wt + (size_t)(rg * 4) * C_ * D_;

  float tot[4][2][4];
#pragma unroll
  for (int m = 0; m < 4; ++m)
#pragma unroll
    for (int n = 0; n < 2; ++n)
#pragma unroll
      for (int j = 0; j < 4; ++j) tot[m][n][j] = 0.f;

  f32x4 acc[4][2];

  // prologue: stage tile 0 via regs
  {
    uint4 la[2], lb[2];
#pragma unroll
    for (int q = 0; q < 2; ++q) {
      la[q] = *reinterpret_cast<const uint4*>(xsrc + a_goff[q]);
      lb[q] = *reinterpret_cast<const uint4*>(wbase + b_goff[q]);
    }
#pragma unroll
    for (int q = 0; q < 2; ++q) {
      *reinterpret_cast<uint4*>((char*)x_s[0] + a_ldst[q]) = la[q];
      *reinterpret_cast<uint4*>((char*)w_s[0] + b_ldst[q]) = lb[q];
    }
  }
  __syncthreads();

  int cur = 0;
  for (int s = 0; s < 32; ++s) {
    const int g = s >> 3, kk = s & 7;
    if (kk == 0) {
#pragma unroll
      for (int m = 0; m < 4; ++m)
#pragma unroll
        for (int n = 0; n < 2; ++n)
          acc[m][n] = f32x4{0.f, 0.f, 0.f, 0.f};
    }
    // issue next tile's global loads early (overlap with ds_read+MFMA below)
    uint4 la[2], lb[2];
    if (s + 1 < 32) {
      const int s1 = s + 1;
      const unsigned short* xs1 = xsrc + (s1 & 7) * 64;
      const unsigned short* ws1 = wbase + (size_t)(s1 >> 3) * C_ * D_ + (s1 & 7) * 64;
#pragma unroll
      for (int q = 0; q < 2; ++q) {
        la[q] = *reinterpret_cast<const uint4*>(xs1 + a_goff[q]);
        lb[q] = *reinterpret_cast<const uint4*>(ws1 + b_goff[q]);
      }
    }
    const char* xb = (const char*)x_s[cur];
    const char* wb = (const char*)w_s[cur];
#pragma unroll
    for (int ks = 0; ks < 2; ++ks) {
      bf16x8 av[4], bv[2];
#pragma unroll
      for (int m = 0; m < 4; ++m)
        av[m] = *reinterpret_cast<const bf16x8*>(xb + offA[m][ks]);
#pragma unroll
      for (int n = 0; n < 2; ++n)
        bv[n] = *reinterpret_cast<const bf16x8*>(wb + offB[n][ks]);
#pragma unroll
      for (int m = 0; m < 4; ++m)
#pragma unroll
        for (int n = 0; n < 2; ++n)
          acc[m][n] = __builtin_amdgcn_mfma_f32_16x16x32_bf16(av[m], bv[n], acc[m][n], 0, 0, 0);
    }
    if (kk == 7) {  // rule g finished: relu(+bias) * fire, accumulate
#pragma unroll
      for (int m = 0; m < 4; ++m)
#pragma unroll
        for (int n = 0; n < 2; ++n) {
          int col = wn * 32 + n * 16 + l16;
          float bi = bias_s[g * 128 + col];
#pragma unroll
          for (int j = 0; j < 4; ++j) {
            int rowl = wm * 64 + m * 16 + lhi * 4 + j;
            float v = acc[m][n][j] + bi;
            v = fmaxf(v, 0.f);
            tot[m][n][j] += v * fire_s[rowl * 4 + g];
          }
        }
    }
    if (s + 1 < 32) {
#pragma unroll
      for (int q = 0; q < 2; ++q) {
        *reinterpret_cast<uint4*>((char*)x_s[cur ^ 1] + a_ldst[q]) = la[q];
        *reinterpret_cast<uint4*>((char*)w_s[cur ^ 1] + b_ldst[q]) = lb[q];
      }
    }
    __syncthreads();
    cur ^= 1;
  }

#pragma unroll
  for (int m = 0; m < 4; ++m)
#pragma unroll
    for (int n = 0; n < 2; ++n) {
      int col = wn * 32 + n * 16 + l16;
#pragma unroll
      for (int j = 0; j < 4; ++j) {
        int rowl = wm * 64 + m * 16 + lhi * 4 + j;
        atomicAdd(&out[(size_t)(b0 + rowl) * C_ + col], tot[m][n][j]);
      }
    }
}

extern "C" void kernel_launch(void* const* d_in, const int* in_sizes, int n_in,
                              void* d_out, int out_size, void* d_ws, size_t ws_size,
                              hipStream_t stream) {
  const float* x     = (const float*)d_in[0];
  const float* proto = (const float*)d_in[1];
  const float* var   = (const float*)d_in[2];
  const float* W     = (const float*)d_in[3];
  const float* bias  = (const float*)d_in[4];
  float* out  = (float*)d_out;
  float* fire = out + (size_t)B_ * C_;   // second output region (also fs_ini accumulator)

  const size_t WS_X  = (size_t)B_ * D_ * sizeof(unsigned short);       // 4 MiB
  const size_t WS_WT = (size_t)R_ * C_ * D_ * sizeof(unsigned short);  // 8 MiB
  const size_t WS_PS = (size_t)R_ * D_ * 2 * sizeof(float);            // 256 KiB
  if (ws_size < WS_X + WS_WT + WS_PS) return;  // insufficient scratch -> visible failure

  unsigned short* xw  = (unsigned short*)d_ws;
  unsigned short* wtp = (unsigned short*)((char*)d_ws + WS_X);
  float*          ps  = (float*)((char*)d_ws + WS_X + WS_WT);

  // zero BOTH output regions: out accumulates gemm atomics, fire accumulates fs partials
  hipMemsetAsync(d_out, 0, (size_t)out_size * sizeof(float), stream);
  prep_wps_kernel<<<dim3(4096 + R_ * D_ / 256), dim3(256), 0, stream>>>(W, wtp, proto, var, ps);
  fs_partial_kernel<<<dim3(B_ / 16, 16), dim3(256), 0, stream>>>(x, ps, fire, xw);
  softmax_kernel<<<dim3(B_ / 4), dim3(256), 0, stream>>>(fire);
  gemm_kernel<<<dim3(512), dim3(512), 0, stream>>>(xw, wtp, fire, bias, out);
}